// Round 1
// baseline (7628.322 us; speedup 1.0000x reference)
//
#include <hip/hip_runtime.h>

#define N_NODES 100000
#define N_EDGES 1000000
#define D 128
#define LN_EPS 1e-5f
#define CNT_EPS 1e-10f

#define ROWRED(v) { v += __shfl_xor(v, 1); v += __shfl_xor(v, 2); \
                    v += __shfl_xor(v, 4); v += __shfl_xor(v, 8); }

// ---------------------------------------------------------------------------
// Edge update: for each edge e: ctx = [edge_f[e] | node_f[src] | node_f[tgt]]
// x = edge_f[e] + ctx @ We + be ;  new_edge = LN(x)*gamma+beta
// fused: atomicAdd new_edge into edge_sum[src], edge_sum[tgt]; count += 1 each
// BM=64 edges/block, BN=128, BK=32, 256 threads, 4x8 micro-tile per thread.
// ---------------------------------------------------------------------------
__launch_bounds__(256)
__global__ void edge_kernel(const float* __restrict__ nodef,
                            const float* __restrict__ edgef,
                            const int*   __restrict__ eidx,
                            const float* __restrict__ We,
                            const float* __restrict__ be,
                            const float* __restrict__ gamma_e,
                            const float* __restrict__ beta_e,
                            float* __restrict__ new_edges,
                            float* __restrict__ edge_sum,
                            float* __restrict__ cnt)
{
    __shared__ float As[32][68];     // [k][row], padded to keep 16B alignment
    __shared__ float Bs[32][128];    // [k][col]
    __shared__ int   s_src[64], s_tgt[64];

    const int tid = threadIdx.x;
    const int e0  = blockIdx.x * 64;

    if (tid < 64)       s_src[tid]      = eidx[e0 + tid];
    else if (tid < 128) s_tgt[tid - 64] = eidx[N_EDGES + e0 + (tid - 64)];
    __syncthreads();

    const int tr = tid >> 4;          // 0..15 -> rows tr*4..tr*4+3
    const int tc = tid & 15;          // 0..15 -> cols tc*8..tc*8+7
    const int lr  = tid >> 2;         // A-load row 0..63
    const int lk0 = (tid & 3) * 8;    // A-load k offset within tile

    float acc[4][8] = {};

    for (int kt = 0; kt < 12; ++kt) {
        // ---- global -> regs ----
        float4 breg[4];
        const float4* bsrc = (const float4*)(We + (size_t)kt * 4096);
        #pragma unroll
        for (int i = 0; i < 4; ++i) breg[i] = bsrc[tid + i * 256];

        const float* abase;
        if (kt < 4)      abase = edgef + (size_t)(e0 + lr) * D + kt * 32;
        else if (kt < 8) abase = nodef + (size_t)s_src[lr] * D + (kt - 4) * 32;
        else             abase = nodef + (size_t)s_tgt[lr] * D + (kt - 8) * 32;
        const float4 a0 = ((const float4*)(abase + lk0))[0];
        const float4 a1 = ((const float4*)(abase + lk0))[1];

        __syncthreads();   // previous tile fully consumed

        // ---- regs -> LDS ----
        #pragma unroll
        for (int i = 0; i < 4; ++i)
            ((float4*)&Bs[0][0])[tid + i * 256] = breg[i];
        {
            const float a[8] = {a0.x, a0.y, a0.z, a0.w, a1.x, a1.y, a1.z, a1.w};
            #pragma unroll
            for (int j = 0; j < 8; ++j) As[lk0 + j][lr] = a[j];
        }
        __syncthreads();

        // ---- compute ----
        #pragma unroll
        for (int kk = 0; kk < 32; ++kk) {
            const float4 av  = *(const float4*)&As[kk][tr * 4];
            const float4 bv0 = *(const float4*)&Bs[kk][tc * 8];
            const float4 bv1 = *(const float4*)&Bs[kk][tc * 8 + 4];
            const float a_[4] = {av.x, av.y, av.z, av.w};
            const float b_[8] = {bv0.x, bv0.y, bv0.z, bv0.w,
                                 bv1.x, bv1.y, bv1.z, bv1.w};
            #pragma unroll
            for (int m = 0; m < 4; ++m)
                #pragma unroll
                for (int n = 0; n < 8; ++n)
                    acc[m][n] = fmaf(a_[m], b_[n], acc[m][n]);
        }
    }

    // ---- epilogue: residual + bias + LN + store + scatter ----
    float g[8], bt[8], bias[8];
    #pragma unroll
    for (int j = 0; j < 8; ++j) {
        g[j]    = gamma_e[tc * 8 + j];
        bt[j]   = beta_e[tc * 8 + j];
        bias[j] = be[tc * 8 + j];
    }

    #pragma unroll
    for (int m = 0; m < 4; ++m) {
        const int row = tr * 4 + m;
        const size_t e = (size_t)e0 + row;
        const float4 r0 = ((const float4*)(edgef + e * D + tc * 8))[0];
        const float4 r1 = ((const float4*)(edgef + e * D + tc * 8))[1];
        float x[8] = {acc[m][0] + bias[0] + r0.x, acc[m][1] + bias[1] + r0.y,
                      acc[m][2] + bias[2] + r0.z, acc[m][3] + bias[3] + r0.w,
                      acc[m][4] + bias[4] + r1.x, acc[m][5] + bias[5] + r1.y,
                      acc[m][6] + bias[6] + r1.z, acc[m][7] + bias[7] + r1.w};
        float s = 0.f;
        #pragma unroll
        for (int j = 0; j < 8; ++j) s += x[j];
        ROWRED(s);
        const float mean = s * 0.0078125f;
        float vs = 0.f;
        #pragma unroll
        for (int j = 0; j < 8; ++j) { const float d = x[j] - mean; vs = fmaf(d, d, vs); }
        ROWRED(vs);
        const float rstd = rsqrtf(vs * 0.0078125f + LN_EPS);

        float y[8];
        #pragma unroll
        for (int j = 0; j < 8; ++j) y[j] = fmaf((x[j] - mean) * rstd, g[j], bt[j]);

        ((float4*)(new_edges + e * D + tc * 8))[0] = make_float4(y[0], y[1], y[2], y[3]);
        ((float4*)(new_edges + e * D + tc * 8))[1] = make_float4(y[4], y[5], y[6], y[7]);

        const int sn = s_src[row], tn = s_tgt[row];
        float* ps = edge_sum + (size_t)sn * D + tc * 8;
        float* pt = edge_sum + (size_t)tn * D + tc * 8;
        #pragma unroll
        for (int j = 0; j < 8; ++j) atomicAdd(&ps[j], y[j]);
        #pragma unroll
        for (int j = 0; j < 8; ++j) atomicAdd(&pt[j], y[j]);
        if (tc == 0) { atomicAdd(&cnt[sn], 1.0f); atomicAdd(&cnt[tn], 1.0f); }
    }
}

// ---------------------------------------------------------------------------
// Node update: ctx = [node_f[n] | edge_sum[n]/(cnt[n]+eps)]
// x = node_f[n] + ctx @ Wn + bn ; new_node = LN(x)*gamma+beta
// edge_sum lives in the new_nodes region of d_out; overwritten in place
// (each block only reads its own rows, all reads precede the final write).
// ---------------------------------------------------------------------------
__launch_bounds__(256)
__global__ void node_kernel(const float* __restrict__ nodef,
                            const float* __restrict__ Wn,
                            const float* __restrict__ bn,
                            const float* __restrict__ gamma_n,
                            const float* __restrict__ beta_n,
                            const float* __restrict__ edge_sum,
                            const float* __restrict__ cnt,
                            float* __restrict__ new_nodes)
{
    __shared__ float As[32][68];
    __shared__ float Bs[32][128];
    __shared__ float s_inv[64];

    const int tid = threadIdx.x;
    const int n0  = blockIdx.x * 64;

    if (tid < 64) {
        const int n = n0 + tid;
        const float c = (n < N_NODES) ? cnt[n] : 0.0f;
        s_inv[tid] = 1.0f / (c + CNT_EPS);
    }
    __syncthreads();

    const int tr = tid >> 4;
    const int tc = tid & 15;
    const int lr  = tid >> 2;
    const int lk0 = (tid & 3) * 8;
    const int nclamp = min(n0 + lr, N_NODES - 1);

    float acc[4][8] = {};

    for (int kt = 0; kt < 8; ++kt) {
        float4 breg[4];
        const float4* bsrc = (const float4*)(Wn + (size_t)kt * 4096);
        #pragma unroll
        for (int i = 0; i < 4; ++i) breg[i] = bsrc[tid + i * 256];

        const float* abase;
        float scale;
        if (kt < 4) { abase = nodef    + (size_t)nclamp * D + kt * 32;       scale = 1.0f; }
        else        { abase = edge_sum + (size_t)nclamp * D + (kt - 4) * 32; scale = s_inv[lr]; }
        float4 a0 = ((const float4*)(abase + lk0))[0];
        float4 a1 = ((const float4*)(abase + lk0))[1];
        a0.x *= scale; a0.y *= scale; a0.z *= scale; a0.w *= scale;
        a1.x *= scale; a1.y *= scale; a1.z *= scale; a1.w *= scale;

        __syncthreads();

        #pragma unroll
        for (int i = 0; i < 4; ++i)
            ((float4*)&Bs[0][0])[tid + i * 256] = breg[i];
        {
            const float a[8] = {a0.x, a0.y, a0.z, a0.w, a1.x, a1.y, a1.z, a1.w};
            #pragma unroll
            for (int j = 0; j < 8; ++j) As[lk0 + j][lr] = a[j];
        }
        __syncthreads();

        #pragma unroll
        for (int kk = 0; kk < 32; ++kk) {
            const float4 av  = *(const float4*)&As[kk][tr * 4];
            const float4 bv0 = *(const float4*)&Bs[kk][tc * 8];
            const float4 bv1 = *(const float4*)&Bs[kk][tc * 8 + 4];
            const float a_[4] = {av.x, av.y, av.z, av.w};
            const float b_[8] = {bv0.x, bv0.y, bv0.z, bv0.w,
                                 bv1.x, bv1.y, bv1.z, bv1.w};
            #pragma unroll
            for (int m = 0; m < 4; ++m)
                #pragma unroll
                for (int n = 0; n < 8; ++n)
                    acc[m][n] = fmaf(a_[m], b_[n], acc[m][n]);
        }
    }

    float g[8], bt[8], bias[8];
    #pragma unroll
    for (int j = 0; j < 8; ++j) {
        g[j]    = gamma_n[tc * 8 + j];
        bt[j]   = beta_n[tc * 8 + j];
        bias[j] = bn[tc * 8 + j];
    }

    #pragma unroll
    for (int m = 0; m < 4; ++m) {
        const int row = tr * 4 + m;
        const int n = n0 + row;
        const size_t nr = (size_t)min(n, N_NODES - 1);
        const float4 r0 = ((const float4*)(nodef + nr * D + tc * 8))[0];
        const float4 r1 = ((const float4*)(nodef + nr * D + tc * 8))[1];
        float x[8] = {acc[m][0] + bias[0] + r0.x, acc[m][1] + bias[1] + r0.y,
                      acc[m][2] + bias[2] + r0.z, acc[m][3] + bias[3] + r0.w,
                      acc[m][4] + bias[4] + r1.x, acc[m][5] + bias[5] + r1.y,
                      acc[m][6] + bias[6] + r1.z, acc[m][7] + bias[7] + r1.w};
        float s = 0.f;
        #pragma unroll
        for (int j = 0; j < 8; ++j) s += x[j];
        ROWRED(s);
        const float mean = s * 0.0078125f;
        float vs = 0.f;
        #pragma unroll
        for (int j = 0; j < 8; ++j) { const float d = x[j] - mean; vs = fmaf(d, d, vs); }
        ROWRED(vs);
        const float rstd = rsqrtf(vs * 0.0078125f + LN_EPS);

        if (n < N_NODES) {
            float y[8];
            #pragma unroll
            for (int j = 0; j < 8; ++j) y[j] = fmaf((x[j] - mean) * rstd, g[j], bt[j]);
            ((float4*)(new_nodes + (size_t)n * D + tc * 8))[0] = make_float4(y[0], y[1], y[2], y[3]);
            ((float4*)(new_nodes + (size_t)n * D + tc * 8))[1] = make_float4(y[4], y[5], y[6], y[7]);
        }
    }
}

extern "C" void kernel_launch(void* const* d_in, const int* in_sizes, int n_in,
                              void* d_out, int out_size, void* d_ws, size_t ws_size,
                              hipStream_t stream) {
    const float* nodef   = (const float*)d_in[0];
    const float* edgef   = (const float*)d_in[1];
    const int*   eidx    = (const int*)d_in[2];
    const float* We      = (const float*)d_in[3];
    const float* be      = (const float*)d_in[4];
    const float* gamma_e = (const float*)d_in[5];
    const float* beta_e  = (const float*)d_in[6];
    const float* Wn      = (const float*)d_in[7];
    const float* bn      = (const float*)d_in[8];
    const float* gamma_n = (const float*)d_in[9];
    const float* beta_n  = (const float*)d_in[10];

    float* new_nodes = (float*)d_out;                      // also edge_sum accumulator
    float* new_edges = (float*)d_out + (size_t)N_NODES * D;
    float* cnt       = (float*)d_ws;                       // N_NODES floats

    hipMemsetAsync(new_nodes, 0, (size_t)N_NODES * D * sizeof(float), stream);
    hipMemsetAsync(cnt,       0, (size_t)N_NODES * sizeof(float), stream);

    edge_kernel<<<N_EDGES / 64, 256, 0, stream>>>(
        nodef, edgef, eidx, We, be, gamma_e, beta_e, new_edges, new_nodes, cnt);
    node_kernel<<<(N_NODES + 63) / 64, 256, 0, stream>>>(
        nodef, Wn, bn, gamma_n, beta_n, new_nodes, cnt, new_nodes);
}

// Round 2
// 2169.090 us; speedup vs baseline: 3.5168x; 3.5168x over previous
//
#include <hip/hip_runtime.h>

#define N_NODES 100000
#define N_EDGES 1000000
#define D 128
#define LN_EPS 1e-5f
#define CNT_EPS 1e-10f

#define ROWRED(v) { v += __shfl_xor(v, 1); v += __shfl_xor(v, 2); \
                    v += __shfl_xor(v, 4); v += __shfl_xor(v, 8); }

// ---------------------------------------------------------------------------
// Edge update (no scatter): x = edge_f + [edge_f|node_f[src]|node_f[tgt]] @ We
// + be ; new_edge = LN(x)*gamma+beta
// ---------------------------------------------------------------------------
__launch_bounds__(256)
__global__ void edge_kernel(const float* __restrict__ nodef,
                            const float* __restrict__ edgef,
                            const int*   __restrict__ eidx,
                            const float* __restrict__ We,
                            const float* __restrict__ be,
                            const float* __restrict__ gamma_e,
                            const float* __restrict__ beta_e,
                            float* __restrict__ new_edges)
{
    __shared__ float As[32][68];
    __shared__ float Bs[32][128];
    __shared__ int   s_src[64], s_tgt[64];

    const int tid = threadIdx.x;
    const int e0  = blockIdx.x * 64;

    if (tid < 64)       s_src[tid]      = eidx[e0 + tid];
    else if (tid < 128) s_tgt[tid - 64] = eidx[N_EDGES + e0 + (tid - 64)];
    __syncthreads();

    const int tr = tid >> 4;
    const int tc = tid & 15;
    const int lr  = tid >> 2;
    const int lk0 = (tid & 3) * 8;

    float acc[4][8] = {};

    for (int kt = 0; kt < 12; ++kt) {
        float4 breg[4];
        const float4* bsrc = (const float4*)(We + (size_t)kt * 4096);
        #pragma unroll
        for (int i = 0; i < 4; ++i) breg[i] = bsrc[tid + i * 256];

        const float* abase;
        if (kt < 4)      abase = edgef + (size_t)(e0 + lr) * D + kt * 32;
        else if (kt < 8) abase = nodef + (size_t)s_src[lr] * D + (kt - 4) * 32;
        else             abase = nodef + (size_t)s_tgt[lr] * D + (kt - 8) * 32;
        const float4 a0 = ((const float4*)(abase + lk0))[0];
        const float4 a1 = ((const float4*)(abase + lk0))[1];

        __syncthreads();

        #pragma unroll
        for (int i = 0; i < 4; ++i)
            ((float4*)&Bs[0][0])[tid + i * 256] = breg[i];
        {
            const float a[8] = {a0.x, a0.y, a0.z, a0.w, a1.x, a1.y, a1.z, a1.w};
            #pragma unroll
            for (int j = 0; j < 8; ++j) As[lk0 + j][lr] = a[j];
        }
        __syncthreads();

        #pragma unroll
        for (int kk = 0; kk < 32; ++kk) {
            const float4 av  = *(const float4*)&As[kk][tr * 4];
            const float4 bv0 = *(const float4*)&Bs[kk][tc * 8];
            const float4 bv1 = *(const float4*)&Bs[kk][tc * 8 + 4];
            const float a_[4] = {av.x, av.y, av.z, av.w};
            const float b_[8] = {bv0.x, bv0.y, bv0.z, bv0.w,
                                 bv1.x, bv1.y, bv1.z, bv1.w};
            #pragma unroll
            for (int m = 0; m < 4; ++m)
                #pragma unroll
                for (int n = 0; n < 8; ++n)
                    acc[m][n] = fmaf(a_[m], b_[n], acc[m][n]);
        }
    }

    float g[8], bt[8], bias[8];
    #pragma unroll
    for (int j = 0; j < 8; ++j) {
        g[j]    = gamma_e[tc * 8 + j];
        bt[j]   = beta_e[tc * 8 + j];
        bias[j] = be[tc * 8 + j];
    }

    #pragma unroll
    for (int m = 0; m < 4; ++m) {
        const int row = tr * 4 + m;
        const size_t e = (size_t)e0 + row;
        const float4 r0 = ((const float4*)(edgef + e * D + tc * 8))[0];
        const float4 r1 = ((const float4*)(edgef + e * D + tc * 8))[1];
        float x[8] = {acc[m][0] + bias[0] + r0.x, acc[m][1] + bias[1] + r0.y,
                      acc[m][2] + bias[2] + r0.z, acc[m][3] + bias[3] + r0.w,
                      acc[m][4] + bias[4] + r1.x, acc[m][5] + bias[5] + r1.y,
                      acc[m][6] + bias[6] + r1.z, acc[m][7] + bias[7] + r1.w};
        float s = 0.f;
        #pragma unroll
        for (int j = 0; j < 8; ++j) s += x[j];
        ROWRED(s);
        const float mean = s * 0.0078125f;
        float vs = 0.f;
        #pragma unroll
        for (int j = 0; j < 8; ++j) { const float d = x[j] - mean; vs = fmaf(d, d, vs); }
        ROWRED(vs);
        const float rstd = rsqrtf(vs * 0.0078125f + LN_EPS);

        float y[8];
        #pragma unroll
        for (int j = 0; j < 8; ++j) y[j] = fmaf((x[j] - mean) * rstd, g[j], bt[j]);

        ((float4*)(new_edges + e * D + tc * 8))[0] = make_float4(y[0], y[1], y[2], y[3]);
        ((float4*)(new_edges + e * D + tc * 8))[1] = make_float4(y[4], y[5], y[6], y[7]);
    }
}

// ---------------------------------------------------------------------------
// CSR build: count -> scan -> fill
// ---------------------------------------------------------------------------
__global__ void count_kernel(const int* __restrict__ eidx, int* __restrict__ cnt)
{
    const int i = blockIdx.x * blockDim.x + threadIdx.x;
    if (i < 2 * N_EDGES) atomicAdd(&cnt[eidx[i]], 1);
}

__launch_bounds__(1024)
__global__ void scan_kernel(const int* __restrict__ cnt,
                            int* __restrict__ offs,
                            int* __restrict__ cursor)
{
    __shared__ int wsum[16];
    __shared__ int sbase;
    const int tid  = threadIdx.x;
    const int lane = tid & 63;
    const int wid  = tid >> 6;
    if (tid == 0) sbase = 0;
    __syncthreads();

    for (int chunk = 0; chunk < N_NODES; chunk += 1024) {
        const int i = chunk + tid;
        const int v = (i < N_NODES) ? cnt[i] : 0;
        int x = v;
        #pragma unroll
        for (int s = 1; s < 64; s <<= 1) {
            const int t = __shfl_up(x, s);
            if (lane >= s) x += t;
        }
        if (lane == 63) wsum[wid] = x;
        __syncthreads();
        if (tid == 0) {
            int run = sbase;
            #pragma unroll
            for (int w = 0; w < 16; ++w) { const int t = wsum[w]; wsum[w] = run; run += t; }
            sbase = run;
        }
        __syncthreads();
        const int excl = wsum[wid] + x - v;
        if (i < N_NODES) { offs[i] = excl; cursor[i] = excl; }
        __syncthreads();
    }
    if (tid == 0) offs[N_NODES] = sbase;
}

__global__ void fill_kernel(const int* __restrict__ eidx,
                            int* __restrict__ cursor,
                            int* __restrict__ list)
{
    const int i = blockIdx.x * blockDim.x + threadIdx.x;
    if (i < 2 * N_EDGES) {
        const int n   = eidx[i];
        const int pos = atomicAdd(&cursor[n], 1);
        list[pos] = (i < N_EDGES) ? i : i - N_EDGES;
    }
}

// ---------------------------------------------------------------------------
// Aggregation: one wave per node, gather incident new_edges rows, mean.
// Each lane owns 2 of the 128 columns (float2 -> 512B/row per wave).
// ---------------------------------------------------------------------------
__launch_bounds__(256)
__global__ void aggregate_kernel(const float* __restrict__ new_edges,
                                 const int* __restrict__ offs,
                                 const int* __restrict__ list,
                                 float* __restrict__ edge_mean)
{
    const int lane   = threadIdx.x & 63;
    const int gwave  = (blockIdx.x * 256 + threadIdx.x) >> 6;
    const int nwaves = gridDim.x * 4;

    for (int n = gwave; n < N_NODES; n += nwaves) {
        const int beg = offs[n], end = offs[n + 1];
        float ax0 = 0.f, ay0 = 0.f, ax1 = 0.f, ay1 = 0.f;
        float ax2 = 0.f, ay2 = 0.f, ax3 = 0.f, ay3 = 0.f;
        int j = beg;
        for (; j + 4 <= end; j += 4) {
            const int e0 = list[j], e1 = list[j + 1], e2 = list[j + 2], e3 = list[j + 3];
            const float2 v0 = ((const float2*)(new_edges + (size_t)e0 * D))[lane];
            const float2 v1 = ((const float2*)(new_edges + (size_t)e1 * D))[lane];
            const float2 v2 = ((const float2*)(new_edges + (size_t)e2 * D))[lane];
            const float2 v3 = ((const float2*)(new_edges + (size_t)e3 * D))[lane];
            ax0 += v0.x; ay0 += v0.y; ax1 += v1.x; ay1 += v1.y;
            ax2 += v2.x; ay2 += v2.y; ax3 += v3.x; ay3 += v3.y;
        }
        for (; j < end; ++j) {
            const int e = list[j];
            const float2 v = ((const float2*)(new_edges + (size_t)e * D))[lane];
            ax0 += v.x; ay0 += v.y;
        }
        const float sx = (ax0 + ax1) + (ax2 + ax3);
        const float sy = (ay0 + ay1) + (ay2 + ay3);
        const float inv = 1.0f / ((float)(end - beg) + CNT_EPS);
        ((float2*)(edge_mean + (size_t)n * D))[lane] = make_float2(sx * inv, sy * inv);
    }
}

// ---------------------------------------------------------------------------
// Node update: x = node_f + [node_f | edge_mean] @ Wn + bn ; LN.
// edge_mean lives in the new_nodes region of d_out; each block reads only its
// own rows before overwriting them.
// ---------------------------------------------------------------------------
__launch_bounds__(256)
__global__ void node_kernel(const float* __restrict__ nodef,
                            const float* __restrict__ Wn,
                            const float* __restrict__ bn,
                            const float* __restrict__ gamma_n,
                            const float* __restrict__ beta_n,
                            const float* __restrict__ edge_mean,
                            float* __restrict__ new_nodes)
{
    __shared__ float As[32][68];
    __shared__ float Bs[32][128];

    const int tid = threadIdx.x;
    const int n0  = blockIdx.x * 64;

    const int tr = tid >> 4;
    const int tc = tid & 15;
    const int lr  = tid >> 2;
    const int lk0 = (tid & 3) * 8;
    const int nclamp = min(n0 + lr, N_NODES - 1);

    float acc[4][8] = {};

    for (int kt = 0; kt < 8; ++kt) {
        float4 breg[4];
        const float4* bsrc = (const float4*)(Wn + (size_t)kt * 4096);
        #pragma unroll
        for (int i = 0; i < 4; ++i) breg[i] = bsrc[tid + i * 256];

        const float* abase = (kt < 4)
            ? nodef     + (size_t)nclamp * D + kt * 32
            : edge_mean + (size_t)nclamp * D + (kt - 4) * 32;
        const float4 a0 = ((const float4*)(abase + lk0))[0];
        const float4 a1 = ((const float4*)(abase + lk0))[1];

        __syncthreads();

        #pragma unroll
        for (int i = 0; i < 4; ++i)
            ((float4*)&Bs[0][0])[tid + i * 256] = breg[i];
        {
            const float a[8] = {a0.x, a0.y, a0.z, a0.w, a1.x, a1.y, a1.z, a1.w};
            #pragma unroll
            for (int j = 0; j < 8; ++j) As[lk0 + j][lr] = a[j];
        }
        __syncthreads();

        #pragma unroll
        for (int kk = 0; kk < 32; ++kk) {
            const float4 av  = *(const float4*)&As[kk][tr * 4];
            const float4 bv0 = *(const float4*)&Bs[kk][tc * 8];
            const float4 bv1 = *(const float4*)&Bs[kk][tc * 8 + 4];
            const float a_[4] = {av.x, av.y, av.z, av.w};
            const float b_[8] = {bv0.x, bv0.y, bv0.z, bv0.w,
                                 bv1.x, bv1.y, bv1.z, bv1.w};
            #pragma unroll
            for (int m = 0; m < 4; ++m)
                #pragma unroll
                for (int n = 0; n < 8; ++n)
                    acc[m][n] = fmaf(a_[m], b_[n], acc[m][n]);
        }
    }

    float g[8], bt[8], bias[8];
    #pragma unroll
    for (int j = 0; j < 8; ++j) {
        g[j]    = gamma_n[tc * 8 + j];
        bt[j]   = beta_n[tc * 8 + j];
        bias[j] = bn[tc * 8 + j];
    }

    #pragma unroll
    for (int m = 0; m < 4; ++m) {
        const int row = tr * 4 + m;
        const int n = n0 + row;
        const size_t nr = (size_t)min(n, N_NODES - 1);
        const float4 r0 = ((const float4*)(nodef + nr * D + tc * 8))[0];
        const float4 r1 = ((const float4*)(nodef + nr * D + tc * 8))[1];
        float x[8] = {acc[m][0] + bias[0] + r0.x, acc[m][1] + bias[1] + r0.y,
                      acc[m][2] + bias[2] + r0.z, acc[m][3] + bias[3] + r0.w,
                      acc[m][4] + bias[4] + r1.x, acc[m][5] + bias[5] + r1.y,
                      acc[m][6] + bias[6] + r1.z, acc[m][7] + bias[7] + r1.w};
        float s = 0.f;
        #pragma unroll
        for (int j = 0; j < 8; ++j) s += x[j];
        ROWRED(s);
        const float mean = s * 0.0078125f;
        float vs = 0.f;
        #pragma unroll
        for (int j = 0; j < 8; ++j) { const float d = x[j] - mean; vs = fmaf(d, d, vs); }
        ROWRED(vs);
        const float rstd = rsqrtf(vs * 0.0078125f + LN_EPS);

        if (n < N_NODES) {
            float y[8];
            #pragma unroll
            for (int j = 0; j < 8; ++j) y[j] = fmaf((x[j] - mean) * rstd, g[j], bt[j]);
            ((float4*)(new_nodes + (size_t)n * D + tc * 8))[0] = make_float4(y[0], y[1], y[2], y[3]);
            ((float4*)(new_nodes + (size_t)n * D + tc * 8))[1] = make_float4(y[4], y[5], y[6], y[7]);
        }
    }
}

extern "C" void kernel_launch(void* const* d_in, const int* in_sizes, int n_in,
                              void* d_out, int out_size, void* d_ws, size_t ws_size,
                              hipStream_t stream) {
    const float* nodef   = (const float*)d_in[0];
    const float* edgef   = (const float*)d_in[1];
    const int*   eidx    = (const int*)d_in[2];
    const float* We      = (const float*)d_in[3];
    const float* be      = (const float*)d_in[4];
    const float* gamma_e = (const float*)d_in[5];
    const float* beta_e  = (const float*)d_in[6];
    const float* Wn      = (const float*)d_in[7];
    const float* bn      = (const float*)d_in[8];
    const float* gamma_n = (const float*)d_in[9];
    const float* beta_n  = (const float*)d_in[10];

    float* new_nodes = (float*)d_out;                      // also edge_mean buffer
    float* new_edges = (float*)d_out + (size_t)N_NODES * D;

    // workspace layout (ints): cnt | offs | cursor | list
    int* cnt    = (int*)d_ws;                   // N_NODES
    int* offs   = cnt + N_NODES;                // N_NODES + 1
    int* cursor = offs + N_NODES + 1;           // N_NODES
    int* list   = cursor + N_NODES;             // 2 * N_EDGES

    hipMemsetAsync(cnt, 0, (size_t)N_NODES * sizeof(int), stream);

    count_kernel<<<(2 * N_EDGES + 255) / 256, 256, 0, stream>>>(eidx, cnt);
    scan_kernel<<<1, 1024, 0, stream>>>(cnt, offs, cursor);
    fill_kernel<<<(2 * N_EDGES + 255) / 256, 256, 0, stream>>>(eidx, cursor, list);

    edge_kernel<<<N_EDGES / 64, 256, 0, stream>>>(
        nodef, edgef, eidx, We, be, gamma_e, beta_e, new_edges);

    aggregate_kernel<<<2048, 256, 0, stream>>>(new_edges, offs, list, new_nodes);

    node_kernel<<<(N_NODES + 63) / 64, 256, 0, stream>>>(
        nodef, Wn, bn, gamma_n, beta_n, new_nodes, new_nodes);
}

// Round 3
// 1094.014 us; speedup vs baseline: 6.9728x; 1.9827x over previous
//
#include <hip/hip_runtime.h>

#define N_NODES 100000
#define N_EDGES 1000000
#define D 128
#define LN_EPS 1e-5f
#define CNT_EPS 1e-10f

typedef __bf16 bf16x8 __attribute__((ext_vector_type(8)));
typedef float  f32x4  __attribute__((ext_vector_type(4)));

#define ROWRED(v) { v += __shfl_xor(v, 1); v += __shfl_xor(v, 2); \
                    v += __shfl_xor(v, 4); v += __shfl_xor(v, 8); }

// ---------------------------------------------------------------------------
// Prep: Wt[j][k] = bf16(We[k][j])  (128 x 384, fragment-contiguous for MFMA B)
// ---------------------------------------------------------------------------
__global__ void prep_wt(const float* __restrict__ We, __bf16* __restrict__ Wt)
{
    const int t = blockIdx.x * 256 + threadIdx.x;
    if (t < 128 * 384) {
        const int j = t / 384, k = t % 384;
        Wt[t] = (__bf16)We[(size_t)k * 128 + j];
    }
}

// ---------------------------------------------------------------------------
// Edge update via MFMA: x = edge_f + [edge_f|node_f[src]|node_f[tgt]] @ We + be
// new_edge = LN(x)*gamma+beta.  BM=128, 4 waves x (M=32,N=128), BK=32.
// ---------------------------------------------------------------------------
__launch_bounds__(256)
__global__ void edge_kernel(const float* __restrict__ nodef,
                            const float* __restrict__ edgef,
                            const int*   __restrict__ eidx,
                            const __bf16* __restrict__ Wt,
                            const float* __restrict__ be,
                            const float* __restrict__ gamma_e,
                            const float* __restrict__ beta_e,
                            float* __restrict__ new_edges)
{
    __shared__ __bf16 As[128][40];   // [row][k], +8 pad -> <=2-way bank conflict
    __shared__ __bf16 Bt[128][40];   // [col][k]
    __shared__ int s_src[128], s_tgt[128];

    const int tid = threadIdx.x;
    const int e0  = blockIdx.x * 128;

    if (tid < 128) {
        s_src[tid] = eidx[min(e0 + tid, N_EDGES - 1)];
    } else {
        s_tgt[tid - 128] = eidx[N_EDGES + min(e0 + tid - 128, N_EDGES - 1)];
    }
    __syncthreads();

    const int lrow  = tid >> 1;                 // 0..127 staging row
    const int lhalf = tid & 1;                  // 16-element half of BK=32
    const size_t eclamp = (size_t)min(e0 + lrow, N_EDGES - 1);

    const float* edgp = edgef + eclamp * D + lhalf * 16;
    const float* srcp = nodef + (size_t)s_src[lrow] * D + lhalf * 16;
    const float* tgtp = nodef + (size_t)s_tgt[lrow] * D + lhalf * 16;
    const __bf16* wb  = Wt + (size_t)lrow * 384 + lhalf * 16;

    const int wid  = tid >> 6;                  // wave 0..3 -> rows wid*32..+31
    const int lane = tid & 63;
    const int li   = lane & 15;
    const int lg   = lane >> 4;
    const int k0   = lg * 8;                    // fragment k offset

    f32x4 acc[2][8];
    const f32x4 zero = {0.f, 0.f, 0.f, 0.f};
    #pragma unroll
    for (int m = 0; m < 2; ++m)
        #pragma unroll
        for (int n = 0; n < 8; ++n) acc[m][n] = zero;

    for (int kt = 0; kt < 12; ++kt) {
        // ---- global loads (overlap with previous compute) ----
        const float* ab = (kt < 4) ? edgp + kt * 32
                        : (kt < 8) ? srcp + (kt - 4) * 32
                                   : tgtp + (kt - 8) * 32;
        const float4 v0 = ((const float4*)ab)[0];
        const float4 v1 = ((const float4*)ab)[1];
        const float4 v2 = ((const float4*)ab)[2];
        const float4 v3 = ((const float4*)ab)[3];
        const bf16x8 b0 = *(const bf16x8*)(wb + kt * 32);
        const bf16x8 b1 = *(const bf16x8*)(wb + kt * 32 + 8);

        __syncthreads();   // previous tile fully consumed

        bf16x8 a0, a1;
        a0[0] = (__bf16)v0.x; a0[1] = (__bf16)v0.y; a0[2] = (__bf16)v0.z; a0[3] = (__bf16)v0.w;
        a0[4] = (__bf16)v1.x; a0[5] = (__bf16)v1.y; a0[6] = (__bf16)v1.z; a0[7] = (__bf16)v1.w;
        a1[0] = (__bf16)v2.x; a1[1] = (__bf16)v2.y; a1[2] = (__bf16)v2.z; a1[3] = (__bf16)v2.w;
        a1[4] = (__bf16)v3.x; a1[5] = (__bf16)v3.y; a1[6] = (__bf16)v3.z; a1[7] = (__bf16)v3.w;
        *(bf16x8*)&As[lrow][lhalf * 16]     = a0;
        *(bf16x8*)&As[lrow][lhalf * 16 + 8] = a1;
        *(bf16x8*)&Bt[lrow][lhalf * 16]     = b0;
        *(bf16x8*)&Bt[lrow][lhalf * 16 + 8] = b1;
        __syncthreads();

        // ---- MFMA ----
        const bf16x8 af0 = *(const bf16x8*)&As[wid * 32 + li][k0];
        const bf16x8 af1 = *(const bf16x8*)&As[wid * 32 + 16 + li][k0];
        #pragma unroll
        for (int nt = 0; nt < 8; ++nt) {
            const bf16x8 bfr = *(const bf16x8*)&Bt[nt * 16 + li][k0];
            acc[0][nt] = __builtin_amdgcn_mfma_f32_16x16x32_bf16(af0, bfr, acc[0][nt], 0, 0, 0);
            acc[1][nt] = __builtin_amdgcn_mfma_f32_16x16x32_bf16(af1, bfr, acc[1][nt], 0, 0, 0);
        }
    }

    // ---- epilogue: residual + bias + LN + store ----
    float g[8], bt_[8], bias[8];
    #pragma unroll
    for (int nt = 0; nt < 8; ++nt) {
        const int col = nt * 16 + li;
        g[nt]    = gamma_e[col];
        bt_[nt]  = beta_e[col];
        bias[nt] = be[col];
    }

    #pragma unroll
    for (int mt = 0; mt < 2; ++mt) {
        #pragma unroll
        for (int r = 0; r < 4; ++r) {
            const int rl = wid * 32 + mt * 16 + lg * 4 + r;   // C row = (lane>>4)*4+reg
            const int e  = e0 + rl;
            const size_t ec = (size_t)min(e, N_EDGES - 1);
            float x[8];
            float s = 0.f;
            #pragma unroll
            for (int nt = 0; nt < 8; ++nt) {
                x[nt] = acc[mt][nt][r] + bias[nt] + edgef[ec * D + nt * 16 + li];
                s += x[nt];
            }
            ROWRED(s);
            const float mean = s * 0.0078125f;
            float vs = 0.f;
            #pragma unroll
            for (int nt = 0; nt < 8; ++nt) { const float d_ = x[nt] - mean; vs = fmaf(d_, d_, vs); }
            ROWRED(vs);
            const float rstd = rsqrtf(vs * 0.0078125f + LN_EPS);
            if (e < N_EDGES) {
                #pragma unroll
                for (int nt = 0; nt < 8; ++nt)
                    new_edges[ec * D + nt * 16 + li] = fmaf((x[nt] - mean) * rstd, g[nt], bt_[nt]);
            }
        }
    }
}

// ---------------------------------------------------------------------------
// CSR build: count -> scan -> fill
// ---------------------------------------------------------------------------
__global__ void count_kernel(const int* __restrict__ eidx, int* __restrict__ cnt)
{
    const int i = blockIdx.x * blockDim.x + threadIdx.x;
    if (i < 2 * N_EDGES) atomicAdd(&cnt[eidx[i]], 1);
}

__launch_bounds__(1024)
__global__ void scan_kernel(const int* __restrict__ cnt,
                            int* __restrict__ offs,
                            int* __restrict__ cursor)
{
    __shared__ int wsum[16];
    __shared__ int sbase;
    const int tid  = threadIdx.x;
    const int lane = tid & 63;
    const int wid  = tid >> 6;
    if (tid == 0) sbase = 0;
    __syncthreads();

    for (int chunk = 0; chunk < N_NODES; chunk += 1024) {
        const int i = chunk + tid;
        const int v = (i < N_NODES) ? cnt[i] : 0;
        int x = v;
        #pragma unroll
        for (int s = 1; s < 64; s <<= 1) {
            const int t = __shfl_up(x, s);
            if (lane >= s) x += t;
        }
        if (lane == 63) wsum[wid] = x;
        __syncthreads();
        if (tid == 0) {
            int run = sbase;
            #pragma unroll
            for (int w = 0; w < 16; ++w) { const int t = wsum[w]; wsum[w] = run; run += t; }
            sbase = run;
        }
        __syncthreads();
        const int excl = wsum[wid] + x - v;
        if (i < N_NODES) { offs[i] = excl; cursor[i] = excl; }
        __syncthreads();
    }
    if (tid == 0) offs[N_NODES] = sbase;
}

__global__ void fill_kernel(const int* __restrict__ eidx,
                            int* __restrict__ cursor,
                            int* __restrict__ list)
{
    const int i = blockIdx.x * blockDim.x + threadIdx.x;
    if (i < 2 * N_EDGES) {
        const int n   = eidx[i];
        const int pos = atomicAdd(&cursor[n], 1);
        list[pos] = (i < N_EDGES) ? i : i - N_EDGES;
    }
}

// ---------------------------------------------------------------------------
// Aggregation: one wave per node, gather incident new_edges rows, mean.
// ---------------------------------------------------------------------------
__launch_bounds__(256)
__global__ void aggregate_kernel(const float* __restrict__ new_edges,
                                 const int* __restrict__ offs,
                                 const int* __restrict__ list,
                                 float* __restrict__ edge_mean)
{
    const int lane   = threadIdx.x & 63;
    const int gwave  = (blockIdx.x * 256 + threadIdx.x) >> 6;
    const int nwaves = gridDim.x * 4;

    for (int n = gwave; n < N_NODES; n += nwaves) {
        const int beg = offs[n], end = offs[n + 1];
        float ax0 = 0.f, ay0 = 0.f, ax1 = 0.f, ay1 = 0.f;
        float ax2 = 0.f, ay2 = 0.f, ax3 = 0.f, ay3 = 0.f;
        int j = beg;
        for (; j + 4 <= end; j += 4) {
            const int e0 = list[j], e1 = list[j + 1], e2 = list[j + 2], e3 = list[j + 3];
            const float2 v0 = ((const float2*)(new_edges + (size_t)e0 * D))[lane];
            const float2 v1 = ((const float2*)(new_edges + (size_t)e1 * D))[lane];
            const float2 v2 = ((const float2*)(new_edges + (size_t)e2 * D))[lane];
            const float2 v3 = ((const float2*)(new_edges + (size_t)e3 * D))[lane];
            ax0 += v0.x; ay0 += v0.y; ax1 += v1.x; ay1 += v1.y;
            ax2 += v2.x; ay2 += v2.y; ax3 += v3.x; ay3 += v3.y;
        }
        for (; j < end; ++j) {
            const int e = list[j];
            const float2 v = ((const float2*)(new_edges + (size_t)e * D))[lane];
            ax0 += v.x; ay0 += v.y;
        }
        const float sx = (ax0 + ax1) + (ax2 + ax3);
        const float sy = (ay0 + ay1) + (ay2 + ay3);
        const float inv = 1.0f / ((float)(end - beg) + CNT_EPS);
        ((float2*)(edge_mean + (size_t)n * D))[lane] = make_float2(sx * inv, sy * inv);
    }
}

// ---------------------------------------------------------------------------
// Node update (f32 FMA path; only ~100K rows): x = node_f + [node_f|edge_mean]@Wn
// ---------------------------------------------------------------------------
__launch_bounds__(256)
__global__ void node_kernel(const float* __restrict__ nodef,
                            const float* __restrict__ Wn,
                            const float* __restrict__ bn,
                            const float* __restrict__ gamma_n,
                            const float* __restrict__ beta_n,
                            const float* __restrict__ edge_mean,
                            float* __restrict__ new_nodes)
{
    __shared__ float As[32][68];
    __shared__ float Bs[32][128];

    const int tid = threadIdx.x;
    const int n0  = blockIdx.x * 64;

    const int tr = tid >> 4;
    const int tc = tid & 15;
    const int lr  = tid >> 2;
    const int lk0 = (tid & 3) * 8;
    const int nclamp = min(n0 + lr, N_NODES - 1);

    float acc[4][8] = {};

    for (int kt = 0; kt < 8; ++kt) {
        float4 breg[4];
        const float4* bsrc = (const float4*)(Wn + (size_t)kt * 4096);
        #pragma unroll
        for (int i = 0; i < 4; ++i) breg[i] = bsrc[tid + i * 256];

        const float* abase = (kt < 4)
            ? nodef     + (size_t)nclamp * D + kt * 32
            : edge_mean + (size_t)nclamp * D + (kt - 4) * 32;
        const float4 a0 = ((const float4*)(abase + lk0))[0];
        const float4 a1 = ((const float4*)(abase + lk0))[1];

        __syncthreads();

        #pragma unroll
        for (int i = 0; i < 4; ++i)
            ((float4*)&Bs[0][0])[tid + i * 256] = breg[i];
        {
            const float a[8] = {a0.x, a0.y, a0.z, a0.w, a1.x, a1.y, a1.z, a1.w};
            #pragma unroll
            for (int j = 0; j < 8; ++j) As[lk0 + j][lr] = a[j];
        }
        __syncthreads();

        #pragma unroll
        for (int kk = 0; kk < 32; ++kk) {
            const float4 av  = *(const float4*)&As[kk][tr * 4];
            const float4 bv0 = *(const float4*)&Bs[kk][tc * 8];
            const float4 bv1 = *(const float4*)&Bs[kk][tc * 8 + 4];
            const float a_[4] = {av.x, av.y, av.z, av.w};
            const float b_[8] = {bv0.x, bv0.y, bv0.z, bv0.w,
                                 bv1.x, bv1.y, bv1.z, bv1.w};
            #pragma unroll
            for (int m = 0; m < 4; ++m)
                #pragma unroll
                for (int n = 0; n < 8; ++n)
                    acc[m][n] = fmaf(a_[m], b_[n], acc[m][n]);
        }
    }

    float g[8], bt[8], bias[8];
    #pragma unroll
    for (int j = 0; j < 8; ++j) {
        g[j]    = gamma_n[tc * 8 + j];
        bt[j]   = beta_n[tc * 8 + j];
        bias[j] = bn[tc * 8 + j];
    }

    #pragma unroll
    for (int m = 0; m < 4; ++m) {
        const int row = tr * 4 + m;
        const int n = n0 + row;
        const size_t nr = (size_t)min(n, N_NODES - 1);
        const float4 r0 = ((const float4*)(nodef + nr * D + tc * 8))[0];
        const float4 r1 = ((const float4*)(nodef + nr * D + tc * 8))[1];
        float x[8] = {acc[m][0] + bias[0] + r0.x, acc[m][1] + bias[1] + r0.y,
                      acc[m][2] + bias[2] + r0.z, acc[m][3] + bias[3] + r0.w,
                      acc[m][4] + bias[4] + r1.x, acc[m][5] + bias[5] + r1.y,
                      acc[m][6] + bias[6] + r1.z, acc[m][7] + bias[7] + r1.w};
        float s = 0.f;
        #pragma unroll
        for (int j = 0; j < 8; ++j) s += x[j];
        ROWRED(s);
        const float mean = s * 0.0078125f;
        float vs = 0.f;
        #pragma unroll
        for (int j = 0; j < 8; ++j) { const float d = x[j] - mean; vs = fmaf(d, d, vs); }
        ROWRED(vs);
        const float rstd = rsqrtf(vs * 0.0078125f + LN_EPS);

        if (n < N_NODES) {
            float y[8];
            #pragma unroll
            for (int j = 0; j < 8; ++j) y[j] = fmaf((x[j] - mean) * rstd, g[j], bt[j]);
            ((float4*)(new_nodes + (size_t)n * D + tc * 8))[0] = make_float4(y[0], y[1], y[2], y[3]);
            ((float4*)(new_nodes + (size_t)n * D + tc * 8))[1] = make_float4(y[4], y[5], y[6], y[7]);
        }
    }
}

extern "C" void kernel_launch(void* const* d_in, const int* in_sizes, int n_in,
                              void* d_out, int out_size, void* d_ws, size_t ws_size,
                              hipStream_t stream) {
    const float* nodef   = (const float*)d_in[0];
    const float* edgef   = (const float*)d_in[1];
    const int*   eidx    = (const int*)d_in[2];
    const float* We      = (const float*)d_in[3];
    const float* be      = (const float*)d_in[4];
    const float* gamma_e = (const float*)d_in[5];
    const float* beta_e  = (const float*)d_in[6];
    const float* Wn      = (const float*)d_in[7];
    const float* bn      = (const float*)d_in[8];
    const float* gamma_n = (const float*)d_in[9];
    const float* beta_n  = (const float*)d_in[10];

    float* new_nodes = (float*)d_out;                      // also edge_mean buffer
    float* new_edges = (float*)d_out + (size_t)N_NODES * D;

    // workspace layout: Wt (bf16, 128x384) | cnt | offs | cursor | list
    __bf16* Wt  = (__bf16*)d_ws;                       // 98304 B
    int* cnt    = (int*)((char*)d_ws + 98304);         // N_NODES
    int* offs   = cnt + N_NODES;                       // N_NODES + 1
    int* cursor = offs + N_NODES + 1;                  // N_NODES
    int* list   = cursor + N_NODES;                    // 2 * N_EDGES

    hipMemsetAsync(cnt, 0, (size_t)N_NODES * sizeof(int), stream);

    prep_wt<<<192, 256, 0, stream>>>(We, Wt);
    count_kernel<<<(2 * N_EDGES + 255) / 256, 256, 0, stream>>>(eidx, cnt);
    scan_kernel<<<1, 1024, 0, stream>>>(cnt, offs, cursor);
    fill_kernel<<<(2 * N_EDGES + 255) / 256, 256, 0, stream>>>(eidx, cursor, list);

    edge_kernel<<<(N_EDGES + 127) / 128, 256, 0, stream>>>(
        nodef, edgef, eidx, Wt, be, gamma_e, beta_e, new_edges);

    aggregate_kernel<<<2048, 256, 0, stream>>>(new_edges, offs, list, new_nodes);

    node_kernel<<<(N_NODES + 63) / 64, 256, 0, stream>>>(
        nodef, Wn, bn, gamma_n, beta_n, new_nodes, new_nodes);
}

// Round 4
// 928.406 us; speedup vs baseline: 8.2166x; 1.1784x over previous
//
#include <hip/hip_runtime.h>

#define N_NODES 100000
#define N_EDGES 1000000
#define D 128
#define NB ((N_NODES + 255) / 256)   // 391 scan blocks
#define LN_EPS 1e-5f
#define CNT_EPS 1e-10f

typedef __bf16 bf16x8 __attribute__((ext_vector_type(8)));
typedef float  f32x4  __attribute__((ext_vector_type(4)));

#define ROWRED(v) { v += __shfl_xor(v, 1); v += __shfl_xor(v, 2); \
                    v += __shfl_xor(v, 4); v += __shfl_xor(v, 8); }

// ---------------------------------------------------------------------------
// Prep: Wt[j][k] = bf16(We[k][j]) (128x384) ; Wtn[j][k] = bf16(Wn[k][j]) (128x256)
// ---------------------------------------------------------------------------
__global__ void prep_w(const float* __restrict__ We, const float* __restrict__ Wn,
                       __bf16* __restrict__ Wt, __bf16* __restrict__ Wtn)
{
    const int t = blockIdx.x * 256 + threadIdx.x;
    if (t < 128 * 384) {
        const int j = t / 384, k = t % 384;
        Wt[t] = (__bf16)We[(size_t)k * 128 + j];
    } else if (t < 128 * 384 + 128 * 256) {
        const int u = t - 128 * 384;
        const int j = u / 256, k = u % 256;
        Wtn[u] = (__bf16)Wn[(size_t)k * 128 + j];
    }
}

// ---------------------------------------------------------------------------
// Edge update via MFMA, 2-phase double-buffered pipeline.
// BM=128, 4 waves x (M=32,N=128), BK=32, 12 K-steps.
// ---------------------------------------------------------------------------
#define ELOAD(kt) { \
    const float* ab = ((kt) < 4) ? edgp + (kt) * 32 \
                    : ((kt) < 8) ? srcp + ((kt) - 4) * 32 \
                                 : tgtp + ((kt) - 8) * 32; \
    v0 = ((const float4*)ab)[0]; v1 = ((const float4*)ab)[1]; \
    v2 = ((const float4*)ab)[2]; v3 = ((const float4*)ab)[3]; \
    wb0 = *(const bf16x8*)(wbp + (kt) * 32); \
    wb1 = *(const bf16x8*)(wbp + (kt) * 32 + 8); }

#define ESTORE(buf) { \
    bf16x8 a0, a1; \
    a0[0] = (__bf16)v0.x; a0[1] = (__bf16)v0.y; a0[2] = (__bf16)v0.z; a0[3] = (__bf16)v0.w; \
    a0[4] = (__bf16)v1.x; a0[5] = (__bf16)v1.y; a0[6] = (__bf16)v1.z; a0[7] = (__bf16)v1.w; \
    a1[0] = (__bf16)v2.x; a1[1] = (__bf16)v2.y; a1[2] = (__bf16)v2.z; a1[3] = (__bf16)v2.w; \
    a1[4] = (__bf16)v3.x; a1[5] = (__bf16)v3.y; a1[6] = (__bf16)v3.z; a1[7] = (__bf16)v3.w; \
    *(bf16x8*)&As[buf][lrow][lhalf * 16]     = a0; \
    *(bf16x8*)&As[buf][lrow][lhalf * 16 + 8] = a1; \
    *(bf16x8*)&Bt[buf][lrow][lhalf * 16]     = wb0; \
    *(bf16x8*)&Bt[buf][lrow][lhalf * 16 + 8] = wb1; }

#define EMFMA(buf) { \
    const bf16x8 af0 = *(const bf16x8*)&As[buf][wid * 32 + li][k0]; \
    const bf16x8 af1 = *(const bf16x8*)&As[buf][wid * 32 + 16 + li][k0]; \
    _Pragma("unroll") \
    for (int nt = 0; nt < 8; ++nt) { \
        const bf16x8 bfr = *(const bf16x8*)&Bt[buf][nt * 16 + li][k0]; \
        acc[0][nt] = __builtin_amdgcn_mfma_f32_16x16x32_bf16(af0, bfr, acc[0][nt], 0, 0, 0); \
        acc[1][nt] = __builtin_amdgcn_mfma_f32_16x16x32_bf16(af1, bfr, acc[1][nt], 0, 0, 0); \
    } }

__launch_bounds__(256)
__global__ void edge_kernel(const float* __restrict__ nodef,
                            const float* __restrict__ edgef,
                            const int*   __restrict__ eidx,
                            const __bf16* __restrict__ Wt,
                            const float* __restrict__ be,
                            const float* __restrict__ gamma_e,
                            const float* __restrict__ beta_e,
                            float* __restrict__ new_edges,
                            __bf16* __restrict__ sh)
{
    __shared__ __bf16 As[2][128][40];
    __shared__ __bf16 Bt[2][128][40];
    __shared__ int s_src[128], s_tgt[128];

    const int tid = threadIdx.x;
    const int e0  = blockIdx.x * 128;

    if (tid < 128) {
        s_src[tid] = eidx[min(e0 + tid, N_EDGES - 1)];
    } else {
        s_tgt[tid - 128] = eidx[N_EDGES + min(e0 + tid - 128, N_EDGES - 1)];
    }
    __syncthreads();

    const int lrow  = tid >> 1;
    const int lhalf = tid & 1;
    const size_t eclamp = (size_t)min(e0 + lrow, N_EDGES - 1);

    const float* edgp = edgef + eclamp * D + lhalf * 16;
    const float* srcp = nodef + (size_t)s_src[lrow] * D + lhalf * 16;
    const float* tgtp = nodef + (size_t)s_tgt[lrow] * D + lhalf * 16;
    const __bf16* wbp = Wt + (size_t)lrow * 384 + lhalf * 16;

    const int wid  = tid >> 6;
    const int lane = tid & 63;
    const int li   = lane & 15;
    const int lg   = lane >> 4;
    const int k0   = lg * 8;

    f32x4 acc[2][8];
    const f32x4 zero = {0.f, 0.f, 0.f, 0.f};
    #pragma unroll
    for (int m = 0; m < 2; ++m)
        #pragma unroll
        for (int n = 0; n < 8; ++n) acc[m][n] = zero;

    float4 v0, v1, v2, v3;
    bf16x8 wb0, wb1;

    ELOAD(0);
    ESTORE(0);
    #pragma unroll
    for (int kt = 0; kt < 12; ++kt) {
        const int cur = kt & 1;
        if (kt < 11) ELOAD(kt + 1);
        __syncthreads();
        EMFMA(cur);
        if (kt < 11) ESTORE(cur ^ 1);
    }

    // ---- epilogue: residual + bias + LN + store (+ bf16 shadow) ----
    float g[8], bt_[8], bias[8];
    #pragma unroll
    for (int nt = 0; nt < 8; ++nt) {
        const int col = nt * 16 + li;
        g[nt]    = gamma_e[col];
        bt_[nt]  = beta_e[col];
        bias[nt] = be[col];
    }

    #pragma unroll
    for (int mt = 0; mt < 2; ++mt) {
        #pragma unroll
        for (int r = 0; r < 4; ++r) {
            const int rl = wid * 32 + mt * 16 + lg * 4 + r;
            const int e  = e0 + rl;
            const size_t ec = (size_t)min(e, N_EDGES - 1);
            float x[8];
            float s = 0.f;
            #pragma unroll
            for (int nt = 0; nt < 8; ++nt) {
                x[nt] = acc[mt][nt][r] + bias[nt] + edgef[ec * D + nt * 16 + li];
                s += x[nt];
            }
            ROWRED(s);
            const float mean = s * 0.0078125f;
            float vs = 0.f;
            #pragma unroll
            for (int nt = 0; nt < 8; ++nt) { const float d_ = x[nt] - mean; vs = fmaf(d_, d_, vs); }
            ROWRED(vs);
            const float rstd = rsqrtf(vs * 0.0078125f + LN_EPS);
            if (e < N_EDGES) {
                float y[8];
                #pragma unroll
                for (int nt = 0; nt < 8; ++nt)
                    y[nt] = fmaf((x[nt] - mean) * rstd, g[nt], bt_[nt]);
                #pragma unroll
                for (int nt = 0; nt < 8; ++nt)
                    new_edges[ec * D + nt * 16 + li] = y[nt];
                if (sh) {
                    #pragma unroll
                    for (int nt = 0; nt < 8; ++nt)
                        sh[ec * D + nt * 16 + li] = (__bf16)y[nt];
                }
            }
        }
    }
}

// ---------------------------------------------------------------------------
// Node update via MFMA, same pipelined structure. K=256 (nodef | edge_mean).
// edge_mean lives in the new_nodes region; each block only reads its own rows
// before overwriting them in the epilogue.
// ---------------------------------------------------------------------------
#define NLOAD(kt) { \
    const float* ab = ((kt) < 4) ? nodp + (kt) * 32 : aggp + ((kt) - 4) * 32; \
    v0 = ((const float4*)ab)[0]; v1 = ((const float4*)ab)[1]; \
    v2 = ((const float4*)ab)[2]; v3 = ((const float4*)ab)[3]; \
    wb0 = *(const bf16x8*)(wbp + (kt) * 32); \
    wb1 = *(const bf16x8*)(wbp + (kt) * 32 + 8); }

__launch_bounds__(256)
__global__ void node_kernel(const float* __restrict__ nodef,
                            const __bf16* __restrict__ Wtn,
                            const float* __restrict__ bn,
                            const float* __restrict__ gamma_n,
                            const float* __restrict__ beta_n,
                            const float* __restrict__ edge_mean,
                            float* __restrict__ new_nodes)
{
    __shared__ __bf16 As[2][128][40];
    __shared__ __bf16 Bt[2][128][40];

    const int tid = threadIdx.x;
    const int n0  = blockIdx.x * 128;

    const int lrow  = tid >> 1;
    const int lhalf = tid & 1;
    const size_t nclamp = (size_t)min(n0 + lrow, N_NODES - 1);

    const float* nodp = nodef     + nclamp * D + lhalf * 16;
    const float* aggp = edge_mean + nclamp * D + lhalf * 16;
    const __bf16* wbp = Wtn + (size_t)lrow * 256 + lhalf * 16;

    const int wid  = tid >> 6;
    const int lane = tid & 63;
    const int li   = lane & 15;
    const int lg   = lane >> 4;
    const int k0   = lg * 8;

    f32x4 acc[2][8];
    const f32x4 zero = {0.f, 0.f, 0.f, 0.f};
    #pragma unroll
    for (int m = 0; m < 2; ++m)
        #pragma unroll
        for (int n = 0; n < 8; ++n) acc[m][n] = zero;

    float4 v0, v1, v2, v3;
    bf16x8 wb0, wb1;

    NLOAD(0);
    ESTORE(0);
    #pragma unroll
    for (int kt = 0; kt < 8; ++kt) {
        const int cur = kt & 1;
        if (kt < 7) NLOAD(kt + 1);
        __syncthreads();
        EMFMA(cur);
        if (kt < 7) ESTORE(cur ^ 1);
    }

    float g[8], bt_[8], bias[8];
    #pragma unroll
    for (int nt = 0; nt < 8; ++nt) {
        const int col = nt * 16 + li;
        g[nt]    = gamma_n[col];
        bt_[nt]  = beta_n[col];
        bias[nt] = bn[col];
    }

    #pragma unroll
    for (int mt = 0; mt < 2; ++mt) {
        #pragma unroll
        for (int r = 0; r < 4; ++r) {
            const int rl = wid * 32 + mt * 16 + lg * 4 + r;
            const int n  = n0 + rl;
            const size_t nc = (size_t)min(n, N_NODES - 1);
            float x[8];
            float s = 0.f;
            #pragma unroll
            for (int nt = 0; nt < 8; ++nt) {
                x[nt] = acc[mt][nt][r] + bias[nt] + nodef[nc * D + nt * 16 + li];
                s += x[nt];
            }
            ROWRED(s);
            const float mean = s * 0.0078125f;
            float vs = 0.f;
            #pragma unroll
            for (int nt = 0; nt < 8; ++nt) { const float d_ = x[nt] - mean; vs = fmaf(d_, d_, vs); }
            ROWRED(vs);
            const float rstd = rsqrtf(vs * 0.0078125f + LN_EPS);
            if (n < N_NODES) {
                #pragma unroll
                for (int nt = 0; nt < 8; ++nt)
                    new_nodes[nc * D + nt * 16 + li] =
                        fmaf((x[nt] - mean) * rstd, g[nt], bt_[nt]);
            }
        }
    }
}

// ---------------------------------------------------------------------------
// CSR build: count -> hierarchical scan -> fill
// ---------------------------------------------------------------------------
__global__ void count_kernel(const int* __restrict__ eidx, int* __restrict__ cnt)
{
    const int i = blockIdx.x * blockDim.x + threadIdx.x;
    if (i < 2 * N_EDGES) atomicAdd(&cnt[eidx[i]], 1);
}

__global__ void scan1(const int* __restrict__ cnt, int* __restrict__ excl,
                      int* __restrict__ bsum)
{
    const int tid = threadIdx.x, lane = tid & 63, wid = tid >> 6;
    const int i = blockIdx.x * 256 + tid;
    const int v = (i < N_NODES) ? cnt[i] : 0;
    int x = v;
    #pragma unroll
    for (int s = 1; s < 64; s <<= 1) { const int t = __shfl_up(x, s); if (lane >= s) x += t; }
    __shared__ int ws[4], wb[4];
    if (lane == 63) ws[wid] = x;
    __syncthreads();
    if (tid == 0) {
        int run = 0;
        #pragma unroll
        for (int w = 0; w < 4; ++w) { wb[w] = run; run += ws[w]; }
        bsum[blockIdx.x] = run;
    }
    __syncthreads();
    if (i < N_NODES) excl[i] = wb[wid] + x - v;
}

__global__ void scan2(int* __restrict__ bsum, int* __restrict__ offs)
{
    __shared__ int ws[4], wb[4];
    __shared__ int sbase;
    const int tid = threadIdx.x, lane = tid & 63, wid = tid >> 6;
    if (tid == 0) sbase = 0;
    __syncthreads();
    for (int chunk = 0; chunk < NB; chunk += 256) {
        const int i = chunk + tid;
        const int v = (i < NB) ? bsum[i] : 0;
        int x = v;
        #pragma unroll
        for (int s = 1; s < 64; s <<= 1) { const int t = __shfl_up(x, s); if (lane >= s) x += t; }
        if (lane == 63) ws[wid] = x;
        __syncthreads();
        if (tid == 0) {
            int run = sbase;
            #pragma unroll
            for (int w = 0; w < 4; ++w) { wb[w] = run; run += ws[w]; }
            sbase = run;
        }
        __syncthreads();
        if (i < NB) bsum[i] = wb[wid] + x - v;
        __syncthreads();
    }
    if (tid == 0) offs[N_NODES] = sbase;
}

__global__ void scan3(const int* __restrict__ excl, const int* __restrict__ bsum,
                      int* __restrict__ offs, int* __restrict__ cursor)
{
    const int i = blockIdx.x * 256 + threadIdx.x;
    if (i < N_NODES) {
        const int o = excl[i] + bsum[i >> 8];
        offs[i] = o;
        cursor[i] = o;
    }
}

__global__ void fill_kernel(const int* __restrict__ eidx,
                            int* __restrict__ cursor,
                            int* __restrict__ list)
{
    const int i = blockIdx.x * blockDim.x + threadIdx.x;
    if (i < 2 * N_EDGES) {
        const int n   = eidx[i];
        const int pos = atomicAdd(&cursor[n], 1);
        list[pos] = (i < N_EDGES) ? i : i - N_EDGES;
    }
}

// ---------------------------------------------------------------------------
// Aggregation: one wave per node. SH=true reads the bf16 shadow (4B/lane/row),
// SH=false reads f32 new_edges (8B/lane/row).
// ---------------------------------------------------------------------------
template<bool SH>
__launch_bounds__(256)
__global__ void aggregate_kernel(const float* __restrict__ nef,
                                 const __bf16* __restrict__ sh,
                                 const int* __restrict__ offs,
                                 const int* __restrict__ list,
                                 float* __restrict__ edge_mean)
{
    const int lane   = threadIdx.x & 63;
    const int gwave  = (blockIdx.x * 256 + threadIdx.x) >> 6;
    const int nwaves = gridDim.x * 4;

    for (int n = gwave; n < N_NODES; n += nwaves) {
        const int beg = offs[n], end = offs[n + 1];
        float ax0 = 0.f, ay0 = 0.f, ax1 = 0.f, ay1 = 0.f;
        float ax2 = 0.f, ay2 = 0.f, ax3 = 0.f, ay3 = 0.f;
        int j = beg;
        if (SH) {
            const unsigned int* base = (const unsigned int*)sh;
            for (; j + 4 <= end; j += 4) {
                const int e0 = list[j], e1 = list[j + 1], e2 = list[j + 2], e3 = list[j + 3];
                const unsigned int u0 = base[(size_t)e0 * 64 + lane];
                const unsigned int u1 = base[(size_t)e1 * 64 + lane];
                const unsigned int u2 = base[(size_t)e2 * 64 + lane];
                const unsigned int u3 = base[(size_t)e3 * 64 + lane];
                ax0 += __uint_as_float(u0 << 16); ay0 += __uint_as_float(u0 & 0xffff0000u);
                ax1 += __uint_as_float(u1 << 16); ay1 += __uint_as_float(u1 & 0xffff0000u);
                ax2 += __uint_as_float(u2 << 16); ay2 += __uint_as_float(u2 & 0xffff0000u);
                ax3 += __uint_as_float(u3 << 16); ay3 += __uint_as_float(u3 & 0xffff0000u);
            }
            for (; j < end; ++j) {
                const unsigned int u = base[(size_t)list[j] * 64 + lane];
                ax0 += __uint_as_float(u << 16); ay0 += __uint_as_float(u & 0xffff0000u);
            }
        } else {
            for (; j + 4 <= end; j += 4) {
                const int e0 = list[j], e1 = list[j + 1], e2 = list[j + 2], e3 = list[j + 3];
                const float2 w0 = ((const float2*)(nef + (size_t)e0 * D))[lane];
                const float2 w1 = ((const float2*)(nef + (size_t)e1 * D))[lane];
                const float2 w2 = ((const float2*)(nef + (size_t)e2 * D))[lane];
                const float2 w3 = ((const float2*)(nef + (size_t)e3 * D))[lane];
                ax0 += w0.x; ay0 += w0.y; ax1 += w1.x; ay1 += w1.y;
                ax2 += w2.x; ay2 += w2.y; ax3 += w3.x; ay3 += w3.y;
            }
            for (; j < end; ++j) {
                const float2 w = ((const float2*)(nef + (size_t)list[j] * D))[lane];
                ax0 += w.x; ay0 += w.y;
            }
        }
        const float sx = (ax0 + ax1) + (ax2 + ax3);
        const float sy = (ay0 + ay1) + (ay2 + ay3);
        const float inv = 1.0f / ((float)(end - beg) + CNT_EPS);
        ((float2*)(edge_mean + (size_t)n * D))[lane] = make_float2(sx * inv, sy * inv);
    }
}

extern "C" void kernel_launch(void* const* d_in, const int* in_sizes, int n_in,
                              void* d_out, int out_size, void* d_ws, size_t ws_size,
                              hipStream_t stream) {
    const float* nodef   = (const float*)d_in[0];
    const float* edgef   = (const float*)d_in[1];
    const int*   eidx    = (const int*)d_in[2];
    const float* We      = (const float*)d_in[3];
    const float* be      = (const float*)d_in[4];
    const float* gamma_e = (const float*)d_in[5];
    const float* beta_e  = (const float*)d_in[6];
    const float* Wn      = (const float*)d_in[7];
    const float* bn      = (const float*)d_in[8];
    const float* gamma_n = (const float*)d_in[9];
    const float* beta_n  = (const float*)d_in[10];

    float* new_nodes = (float*)d_out;                      // also edge_mean buffer
    float* new_edges = (float*)d_out + (size_t)N_NODES * D;

    // workspace layout
    char* p = (char*)d_ws;
    __bf16* Wt  = (__bf16*)p;  p += 128 * 384 * 2;     // 98304
    __bf16* Wtn = (__bf16*)p;  p += 128 * 256 * 2;     // 65536
    int* cnt    = (int*)p;     p += (size_t)N_NODES * 4;
    int* excl   = (int*)p;     p += (size_t)N_NODES * 4;
    int* offs   = (int*)p;     p += (size_t)(N_NODES + 2) * 4;
    int* cursor = (int*)p;     p += (size_t)N_NODES * 4;
    int* bsum   = (int*)p;     p += 2048;
    int* list   = (int*)p;     p += (size_t)2 * N_EDGES * 4;
    const size_t base_bytes = (size_t)(p - (char*)d_ws);
    const size_t shadow_bytes = (size_t)N_EDGES * D * 2;
    __bf16* shadow = nullptr;
    if (ws_size >= base_bytes + shadow_bytes) shadow = (__bf16*)p;

    hipMemsetAsync(cnt, 0, (size_t)N_NODES * sizeof(int), stream);

    prep_w<<<320, 256, 0, stream>>>(We, Wn, Wt, Wtn);
    count_kernel<<<(2 * N_EDGES + 255) / 256, 256, 0, stream>>>(eidx, cnt);
    scan1<<<NB, 256, 0, stream>>>(cnt, excl, bsum);
    scan2<<<1, 256, 0, stream>>>(bsum, offs);
    scan3<<<NB, 256, 0, stream>>>(excl, bsum, offs, cursor);
    fill_kernel<<<(2 * N_EDGES + 255) / 256, 256, 0, stream>>>(eidx, cursor, list);

    edge_kernel<<<(N_EDGES + 127) / 128, 256, 0, stream>>>(
        nodef, edgef, eidx, Wt, be, gamma_e, beta_e, new_edges, shadow);

    if (shadow)
        aggregate_kernel<true><<<2048, 256, 0, stream>>>(new_edges, shadow, offs, list, new_nodes);
    else
        aggregate_kernel<false><<<2048, 256, 0, stream>>>(new_edges, nullptr, offs, list, new_nodes);

    node_kernel<<<(N_NODES + 127) / 128, 256, 0, stream>>>(
        nodef, Wtn, bn, gamma_n, beta_n, new_nodes, new_nodes);
}